// Round 2
// baseline (1449.296 us; speedup 1.0000x reference)
//
#include <hip/hip_runtime.h>
#include <math.h>

typedef float f4 __attribute__((ext_vector_type(4)));

#define TOKENS 16384
#define DIM    4096
#define NE     64
#define KTOP   8
#define BK     32
#define TPB    16               // tokens per block (4 per wave x 4 waves)
#define NT     256
#define NKT    (DIM / BK)       // 128 K-steps
#define NBLK   (TOKENS / TPB)   // 1024 blocks -> 4 blocks/CU

#define GAS __attribute__((address_space(1)))
#define LAS __attribute__((address_space(3)))
// async global->LDS, 16B/lane, lane-linear LDS dest (wave-uniform base + lane*16)
#define GLD16(src, dst) \
    __builtin_amdgcn_global_load_lds((const GAS void*)(src), (LAS void*)(dst), 16, 0, 0)

// lane = expert. W tile LDS layout [e][G] holds W[e][k0 + 4*(G ^ (e&7))] (XOR swizzle
// applied on the *global source* address, LDS dest stays linear — rule #21). Read of
// logical k-group g fetches G = g ^ (lane&7): lanes 0..7 hit 8 distinct 16B groups
// = all 32 banks; worst case 2-way aliasing across 8-lane octets (free, m136).
// X tile [t][g] is read at wave-uniform addresses -> pure broadcast, conflict-free.
__global__ __launch_bounds__(NT, 4) void gate_topk_kernel(
    const float* __restrict__ x, const float* __restrict__ W,
    const float* __restrict__ bias, float* __restrict__ idx_out,
    float* __restrict__ val_out, float* __restrict__ blocksums)
{
    __shared__ __align__(16) float Xs[2][TPB * BK];   //  4 KB
    __shared__ __align__(16) float Ws[2][NE * BK];    // 16 KB
    __shared__ float bsum[4];

    const int tid  = threadIdx.x;
    const int lane = tid & 63;
    const int w    = tid >> 6;
    const int row0 = blockIdx.x * TPB;

    const float bv = bias[lane];

    // ---- staging source pointers (per lane); each wave issues 2 W instrs (+1 X if w<2)
    const int sub = lane >> 3;          // row within the instr's 8-row span
    const int grp = lane & 7;           // physical 16B group in LDS
    const int e0  = (2 * w) * 8 + sub;
    const int e1  = (2 * w + 1) * 8 + sub;
    const float* pW0 = W + (size_t)e0 * DIM + ((grp ^ (sub & 7)) << 2);
    const float* pW1 = W + (size_t)e1 * DIM + ((grp ^ (sub & 7)) << 2);
    const float* pX  = x + (size_t)(row0 + w * 8 + sub) * DIM + (grp << 2); // used iff w<2

    // ---- compute-side LDS addresses: fixed base regs, buffer picked via imm offsets
    const int swz = lane & 7;
    const float* wp[8];
#pragma unroll
    for (int g = 0; g < 8; ++g)
        wp[g] = &Ws[0][lane * BK + ((g ^ swz) << 2)];
    const float* xb = &Xs[0][(w * 4) * BK];

    float acc[4] = {0.f, 0.f, 0.f, 0.f};

#define STAGE(b) do {                                   \
        GLD16(pW0, &Ws[b][(2 * w) * 8 * BK]);           \
        GLD16(pW1, &Ws[b][(2 * w + 1) * 8 * BK]);       \
        if (w < 2) GLD16(pX, &Xs[b][w * 8 * BK]);       \
        pW0 += BK; pW1 += BK; pX += BK;                 \
    } while (0)

    // two-level K accumulation (fresh sub-acc per BK step) keeps top-k tie-safe precision
#define COMPUTE(b) do {                                                     \
        float t0 = 0.f, t1 = 0.f, t2 = 0.f, t3 = 0.f;                       \
        _Pragma("unroll")                                                   \
        for (int g = 0; g < 8; ++g) {                                       \
            const f4 wf  = *(const f4*)(wp[g] + (b) * (NE * BK));           \
            const f4 xv0 = *(const f4*)(xb + (b) * (TPB * BK) + 0 * BK + (g << 2)); \
            const f4 xv1 = *(const f4*)(xb + (b) * (TPB * BK) + 1 * BK + (g << 2)); \
            const f4 xv2 = *(const f4*)(xb + (b) * (TPB * BK) + 2 * BK + (g << 2)); \
            const f4 xv3 = *(const f4*)(xb + (b) * (TPB * BK) + 3 * BK + (g << 2)); \
            _Pragma("unroll")                                               \
            for (int j = 0; j < 4; ++j) {                                   \
                t0 = fmaf(xv0[j], wf[j], t0);                               \
                t1 = fmaf(xv1[j], wf[j], t1);                               \
                t2 = fmaf(xv2[j], wf[j], t2);                               \
                t3 = fmaf(xv3[j], wf[j], t3);                               \
            }                                                               \
        }                                                                   \
        acc[0] += t0; acc[1] += t1; acc[2] += t2; acc[3] += t3;             \
    } while (0)

    STAGE(0);
    __syncthreads();                       // vmcnt(0) drain + barrier: buf0 ready
    for (int kt = 0; kt < NKT; kt += 2) {
        STAGE(1);                          // prefetch flies under compute
        COMPUTE(0);
        __syncthreads();
        if (kt + 2 < NKT) STAGE(0);
        COMPUTE(1);
        __syncthreads();
    }
#undef STAGE
#undef COMPUTE

    // ---- epilogue: lane e holds logits[t][e]; softmax + top-8 via shfl butterflies
    float wsum = 0.0f;
#pragma unroll
    for (int tt = 0; tt < 4; ++tt) {
        const float logit = acc[tt] + bv;
        float mx = logit;
#pragma unroll
        for (int off = 32; off > 0; off >>= 1)
            mx = fmaxf(mx, __shfl_xor(mx, off, 64));
        const float p = expf(logit - mx);
        float s = p;
#pragma unroll
        for (int off = 32; off > 0; off >>= 1)
            s += __shfl_xor(s, off, 64);       // identical tree on all lanes
        const float rs = 1.0f / s;
        const int token = row0 + w * 4 + tt;
        float pv = p;
#pragma unroll
        for (int j = 0; j < KTOP; ++j) {
            float v = pv; int e = lane;
#pragma unroll
            for (int off = 1; off < 64; off <<= 1) {   // argmax, lower idx wins ties
                const float v2 = __shfl_xor(v, off, 64);
                const int   e2 = __shfl_xor(e, off, 64);
                if (v2 > v || (v2 == v && e2 < e)) { v = v2; e = e2; }
            }
            const float val = v * rs;
            if (lane == j) {
                idx_out[token * KTOP + j] = (float)e;   // d_out read back as flat f32
                val_out[token * KTOP + j] = val;        // raw; normalized by K2
            }
            if (lane == e) pv = -1.0f;
            wsum += val;                                // uniform across lanes
        }
    }
    if (lane == 0) bsum[w] = wsum;
    __syncthreads();
    if (tid == 0)
        blocksums[blockIdx.x] = bsum[0] + bsum[1] + bsum[2] + bsum[3];
}

// K2: weights = vals / sum(all vals). Every block redundantly reduces the 1024
// partials (fixed order -> deterministic), then scales its slice in place.
__global__ __launch_bounds__(256) void scale_kernel(
    const float* __restrict__ blocksums, float* __restrict__ vals)
{
    __shared__ float sred[4];
    const int tid = threadIdx.x;
    const f4 v4 = *(const f4*)(blocksums + tid * 4);   // 256 threads x 4 = 1024
    float s = v4[0] + v4[1] + v4[2] + v4[3];
#pragma unroll
    for (int off = 32; off > 0; off >>= 1)
        s += __shfl_xor(s, off, 64);
    if ((tid & 63) == 0) sred[tid >> 6] = s;
    __syncthreads();
    const float total = sred[0] + sred[1] + sred[2] + sred[3];
    const int i = blockIdx.x * 256 + tid;
    vals[i] = vals[i] / total;
}

extern "C" void kernel_launch(void* const* d_in, const int* in_sizes, int n_in,
                              void* d_out, int out_size, void* d_ws, size_t ws_size,
                              hipStream_t stream)
{
    const float* x = (const float*)d_in[0];
    const float* W = (const float*)d_in[1];
    const float* b = (const float*)d_in[2];
    float* idx_out = (float*)d_out;
    float* val_out = idx_out + (size_t)TOKENS * KTOP;
    float* blocksums = (float*)d_ws;

    gate_topk_kernel<<<NBLK, NT, 0, stream>>>(x, W, b, idx_out, val_out, blocksums);
    scale_kernel<<<(TOKENS * KTOP) / 256, 256, 0, stream>>>(blocksums, val_out);
}

// Round 4
// 348.232 us; speedup vs baseline: 4.1619x; 4.1619x over previous
//
#include <hip/hip_runtime.h>
#include <math.h>

typedef float f4 __attribute__((ext_vector_type(4)));

#define TOKENS 16384
#define DIM    4096
#define NE     64
#define KTOP   8
#define BM     64
#define BK     64
#define NGRP   4                 // in-block K-split groups
#define KRANGE (DIM / NGRP)      // 1024 K per group
#define NTILE  (KRANGE / BK)     // 16 tiles per group
#define NT     1024              // 16 waves/block
#define NBLK   (TOKENS / BM)     // 256 blocks = 1 block/CU, 16 waves/CU

// K1: gate GEMM (in-block K-split-4) + softmax + top-8.
// Each 256-thread group = round-1 proven core: 4x4 register tile, BK=64,
// XOR-swizzled LDS (element [kk][m] at kk*64 + (((m>>2)^(kk>>2))&15)*4 + (m&3)),
// register prefetch of the next K-tile. Groups share nothing but barriers.
__global__ __launch_bounds__(NT, 4) void gate_topk_kernel(
    const float* __restrict__ x, const float* __restrict__ W,
    const float* __restrict__ bias, float* __restrict__ idx_out,
    float* __restrict__ val_out, float* __restrict__ blocksums)
{
    __shared__ float smem[NGRP][2][BK * BM];   // [g][0]=As (later P[g]), [g][1]=Bs; 128 KB
    __shared__ float bsum[16];

    const int tid = threadIdx.x;
    const int g   = tid >> 8;      // K-split group 0..3
    const int gt  = tid & 255;     // thread-in-group
    // staging mapping (within group)
    const int kq = gt & 15;        // f4 index along K
    const int mg = gt >> 4;        // base row, rows mg+16s
    // compute mapping: 16x16 thread grid, 4x4 register tile
    const int tx = gt & 15;
    const int ty = gt >> 4;
    const int tm = ty << 2;
    const int tn = tx << 2;
    const int row0 = blockIdx.x * BM;

    float* As = smem[g][0];
    float* Bs = smem[g][1];

    const int kbase = g * KRANGE;
    const float* xa0 = x + (size_t)(row0 + mg) * DIM + kbase + (kq << 2);
    const float* wb0 = W + (size_t)mg * DIM + kbase + (kq << 2);

    float acc[4][4] = {};
    f4 fa[4], fb[4];
#pragma unroll
    for (int s = 0; s < 4; ++s) {
        fa[s] = *(const f4*)(xa0 + (size_t)(16 * s) * DIM);
        fb[s] = *(const f4*)(wb0 + (size_t)(16 * s) * DIM);
    }

    for (int kt = 0; kt < NTILE; ++kt) {
        __syncthreads();   // previous tile's reads done (all groups in lockstep)
#pragma unroll
        for (int s = 0; s < 4; ++s) {
            const int m  = mg + (s << 4);
            const int c4 = ((m >> 2) ^ kq) & 15;
            const int base = (kq << 2) * BM + (c4 << 2) + (m & 3);
#pragma unroll
            for (int j = 0; j < 4; ++j) {
                As[base + (j << 6)] = fa[s][j];
                Bs[base + (j << 6)] = fb[s][j];
            }
        }
        __syncthreads();
        if (kt + 1 < NTILE) {   // prefetch next tile into regs (HBM hides under FMAs)
            const int ko = (kt + 1) * BK;
#pragma unroll
            for (int s = 0; s < 4; ++s) {
                fa[s] = *(const f4*)(xa0 + (size_t)(16 * s) * DIM + ko);
                fb[s] = *(const f4*)(wb0 + (size_t)(16 * s) * DIM + ko);
            }
        }
        // two-level accumulation: fresh sub-acc per K-tile (top-k tie-safe precision)
        float acct[4][4] = {};
#pragma unroll
        for (int kk = 0; kk < BK; ++kk) {
            const int kq2 = kk >> 2;
            const f4 a4 = *(const f4*)&As[kk * BM + (((ty ^ kq2) & 15) << 2)];
            const f4 b4 = *(const f4*)&Bs[kk * NE + (((tx ^ kq2) & 15) << 2)];
#pragma unroll
            for (int i = 0; i < 4; ++i)
#pragma unroll
                for (int j = 0; j < 4; ++j)
                    acct[i][j] = fmaf(a4[i], b4[j], acct[i][j]);
        }
#pragma unroll
        for (int i = 0; i < 4; ++i)
#pragma unroll
            for (int j = 0; j < 4; ++j)
                acc[i][j] += acct[i][j];
    }

    // RACE FIX (round-3 tripwire): the final COMPUTE's ds_reads of As must
    // complete block-wide before any thread overwrites As with partial logits.
    __syncthreads();

    // ---- write partial logits P[g][m][e] over our own As region
#pragma unroll
    for (int i = 0; i < 4; ++i) {
        f4 v = { acc[i][0], acc[i][1], acc[i][2], acc[i][3] };
        *(f4*)&As[(tm + i) * NE + tn] = v;
    }
    __syncthreads();

    // ---- epilogue: wave wv handles tokens 4wv..4wv+3; lane = expert
    const int wv   = tid >> 6;
    const int lane = tid & 63;
    const float bv = bias[lane];
    float wsum = 0.0f;
#pragma unroll
    for (int tt = 0; tt < 4; ++tt) {
        const int t = wv * 4 + tt;
        const int token = row0 + t;
        const float logit = smem[0][0][t * NE + lane] + smem[1][0][t * NE + lane]
                          + smem[2][0][t * NE + lane] + smem[3][0][t * NE + lane] + bv;
        float mx = logit;
#pragma unroll
        for (int off = 32; off > 0; off >>= 1)
            mx = fmaxf(mx, __shfl_xor(mx, off, 64));
        const float p = expf(logit - mx);
        float s = p;
#pragma unroll
        for (int off = 32; off > 0; off >>= 1)
            s += __shfl_xor(s, off, 64);           // identical tree on all lanes
        const float rs = 1.0f / s;
        float pv = p;
#pragma unroll
        for (int j = 0; j < KTOP; ++j) {
            float v = pv; int e = lane;
#pragma unroll
            for (int off = 1; off < 64; off <<= 1) {   // argmax, lower idx wins ties
                const float v2 = __shfl_xor(v, off, 64);
                const int   e2 = __shfl_xor(e, off, 64);
                if (v2 > v || (v2 == v && e2 < e)) { v = v2; e = e2; }
            }
            const float val = v * rs;
            if (lane == j) {
                idx_out[token * KTOP + j] = (float)e;   // d_out read back as flat f32
                val_out[token * KTOP + j] = val;        // raw; normalized by K2
            }
            if (lane == e) pv = -1.0f;
            wsum += val;                                // uniform across lanes
        }
    }
    if (lane == 0) bsum[wv] = wsum;
    __syncthreads();
    if (tid == 0) {
        float t = 0.0f;
#pragma unroll
        for (int i = 0; i < 16; ++i) t += bsum[i];
        blocksums[blockIdx.x] = t;
    }
}

// K2: weights = vals / sum(all vals). Every thread computes the same serial sum
// of 256 partials (uniform -> scalarized, deterministic), then divides in place.
__global__ __launch_bounds__(256) void scale_kernel(
    const float* __restrict__ blocksums, float* __restrict__ vals)
{
    float total = 0.0f;
    for (int i = 0; i < NBLK; ++i) total += blocksums[i];
    const int i = blockIdx.x * blockDim.x + threadIdx.x;
    vals[i] = vals[i] / total;
}

extern "C" void kernel_launch(void* const* d_in, const int* in_sizes, int n_in,
                              void* d_out, int out_size, void* d_ws, size_t ws_size,
                              hipStream_t stream)
{
    const float* x = (const float*)d_in[0];
    const float* W = (const float*)d_in[1];
    const float* b = (const float*)d_in[2];
    float* idx_out = (float*)d_out;
    float* val_out = idx_out + (size_t)TOKENS * KTOP;
    float* blocksums = (float*)d_ws;

    gate_topk_kernel<<<NBLK, NT, 0, stream>>>(x, W, b, idx_out, val_out, blocksums);
    scale_kernel<<<(TOKENS * KTOP) / 256, 256, 0, stream>>>(blocksums, val_out);
}